// Round 8
// baseline (409.769 us; speedup 1.0000x reference)
//
#include <hip/hip_runtime.h>
#include <math.h>

#define BB 2
#define NTOK 784
#define DM 256
#define NH 8
#define DH 32
#define NW 16
#define WS 49
#define KTOP 8
#define MTOT 1568
#define NBLK 256

// ---- workspace offsets (float units) ----
#define O_XF    0
#define O_XH    401408
#define O_XL    602112
#define O_Q     802816
#define O_K     1204224
#define O_V     1605632
#define O_QM    2007040
#define O_KM    2015232
#define O_VM    2023424
#define O_CNT   2031680
#define O_WHI   2031936
#define O_WLO   2359616
#define O_MH    2687296
#define O_ML    2888000
#define O_M2H   3088704
#define O_M2L   3289408
#define O_Y1    3490112
#define O_GH    4292928
#define O_GL    4694336
#define O_BAR   5095744

typedef __attribute__((ext_vector_type(8))) short bhalf8;
typedef __attribute__((ext_vector_type(4))) float floatx4;

__device__ __forceinline__ unsigned short f2b(float f){
  unsigned u = __float_as_uint(f);
  return (unsigned short)((u + 0x7fffu + ((u >> 16) & 1u)) >> 16);
}
__device__ __forceinline__ float b2f(unsigned short h){
  return __uint_as_float(((unsigned)h) << 16);
}
__device__ __forceinline__ void split2(float f, unsigned short* hi, unsigned short* lo){
  unsigned short h = f2b(f);
  *hi = h;
  *lo = f2b(f - b2f(h));
}

// ---- shared memory union (max ~17.3 KB) ----
struct SmemPrep { float tile[32][33]; };
struct SmemTopk { float sim[16][16]; int sidx[16][KTOP]; };
struct SmemAttn { short Kf[2][128][8]; short Vf[2][128][8]; float Wt[800]; short Pl[4][16][40]; };
struct SmemGln  { float Cs[16][261]; float wps[4][16]; float wpq[4][16]; float smu[16]; float srs[16]; };
union Smem {
  SmemPrep p; SmemTopk t; SmemAttn a; SmemGln g;
};

// ---- device-scope grid barrier (256 co-resident blocks; slots pre-zeroed) ----
__device__ __forceinline__ void gsync(int* bars, int slot){
  __syncthreads();
  if (threadIdx.x == 0){
    __hip_atomic_fetch_add(&bars[slot], 1, __ATOMIC_RELEASE, __HIP_MEMORY_SCOPE_AGENT);
    while (__hip_atomic_load(&bars[slot], __ATOMIC_ACQUIRE, __HIP_MEMORY_SCOPE_AGENT) < NBLK){
      __builtin_amdgcn_s_sleep(8);
    }
  }
  __syncthreads();
}

__global__ void k_zero(int* bars){
  if (threadIdx.x < 16) bars[threadIdx.x] = 0;
}

// ---- phase 0: transpose + weight cast ----
__device__ __forceinline__ void ph_prep(int vb, Smem& sm, const float* __restrict__ x,
    float* __restrict__ xf, unsigned short* __restrict__ xh, unsigned short* __restrict__ xl,
    const float* __restrict__ Wq, const float* __restrict__ Wk, const float* __restrict__ Wv,
    const float* __restrict__ Wm, const float* __restrict__ f1, const float* __restrict__ f2,
    unsigned short* __restrict__ dhi, unsigned short* __restrict__ dlo){
  int t = threadIdx.x;
  if (vb < 400){
    int b = vb / 200; int r = vb - b*200;
    int d0 = (r / 25) * 32, n0 = (r % 25) * 32;
    int tx = t & 31, ty = t >> 5;
    #pragma unroll
    for (int i = 0; i < 4; i++){
      int d = d0 + ty + i*8, n = n0 + tx;
      if (n < NTOK) sm.p.tile[ty + i*8][tx] = x[((size_t)b*DM + d)*NTOK + n];
    }
    __syncthreads();
    #pragma unroll
    for (int i = 0; i < 4; i++){
      int n = n0 + ty + i*8, d = d0 + tx;
      if (n < NTOK){
        float v = sm.p.tile[tx][ty + i*8];
        size_t o = ((size_t)b*NTOK + n)*DM + d;
        xf[o] = v;
        unsigned short h, l; split2(v, &h, &l);
        xh[o] = h; xl[o] = l;
      }
    }
    __syncthreads();
  } else {
    int i = ((vb - 400)*256 + t)*4;
    const float* src; int off;
    if (i < 65536){ src=Wq; off=i; }
    else if (i < 131072){ src=Wk; off=i-65536; }
    else if (i < 196608){ src=Wv; off=i-131072; }
    else if (i < 262144){ src=Wm; off=i-196608; }
    else if (i < 524288){ src=f1; off=i-262144; }
    else { src=f2; off=i-524288; }
    float4 fv = *(const float4*)(src + off);
    ushort4 oh, ol;
    split2(fv.x, &oh.x, &ol.x);
    split2(fv.y, &oh.y, &ol.y);
    split2(fv.z, &oh.z, &ol.z);
    split2(fv.w, &oh.w, &ol.w);
    *(ushort4*)(dhi + i) = oh;
    *(ushort4*)(dlo + i) = ol;
  }
}

// ---- split-bf16 MFMA GEMM tile (verified r4) ----
template<int K, int MODE_A, int ACT, bool HASB, int MODE_C>
__device__ __forceinline__ void mgemm_tile(int bx, int by,
    const unsigned short* __restrict__ Ah0, const unsigned short* __restrict__ Al0,
    const unsigned short* __restrict__ Ah1, const unsigned short* __restrict__ Al1,
    const unsigned short* __restrict__ Wh, const unsigned short* __restrict__ Wl,
    const float* __restrict__ bias,
    float* __restrict__ C0, float* __restrict__ C1, float* __restrict__ C2,
    int M, int NN){
  int t = threadIdx.x;
  int w = t >> 6, l = t & 63;
  int lm = l & 15;
  int lk = (l >> 4) << 3;
  int mw = bx * 64 + (w >> 1) * 32;
  int nw = by * 64 + (w & 1) * 32;
  floatx4 acc[2][2] = {};
  int ar0 = mw + lm, ar1 = ar0 + 16;
  int ga0 = (ar0 < M) ? ar0 : 0;
  int ga1 = (ar1 < M) ? ar1 : 0;
  int nr0 = nw + lm, nr1 = nr0 + 16;
  #pragma unroll 4
  for (int k0 = 0; k0 < K; k0 += 32){
    int ak = k0 + lk;
    bhalf8 a0h, a0l, a1h, a1l;
    if (MODE_A == 1){
      const unsigned short* bh = (ak < 256) ? Ah0 : Ah1;
      const unsigned short* bl = (ak < 256) ? Al0 : Al1;
      int col = ak & 255;
      a0h = *(const bhalf8*)(bh + (size_t)ga0*256 + col);
      a0l = *(const bhalf8*)(bl + (size_t)ga0*256 + col);
      a1h = *(const bhalf8*)(bh + (size_t)ga1*256 + col);
      a1l = *(const bhalf8*)(bl + (size_t)ga1*256 + col);
    } else {
      a0h = *(const bhalf8*)(Ah0 + (size_t)ga0*K + ak);
      a0l = *(const bhalf8*)(Al0 + (size_t)ga0*K + ak);
      a1h = *(const bhalf8*)(Ah0 + (size_t)ga1*K + ak);
      a1l = *(const bhalf8*)(Al0 + (size_t)ga1*K + ak);
    }
    bhalf8 w0h = *(const bhalf8*)(Wh + (size_t)nr0*K + ak);
    bhalf8 w0l = *(const bhalf8*)(Wl + (size_t)nr0*K + ak);
    bhalf8 w1h = *(const bhalf8*)(Wh + (size_t)nr1*K + ak);
    bhalf8 w1l = *(const bhalf8*)(Wl + (size_t)nr1*K + ak);
    acc[0][0] = __builtin_amdgcn_mfma_f32_16x16x32_bf16(a0h, w0h, acc[0][0], 0, 0, 0);
    acc[0][0] = __builtin_amdgcn_mfma_f32_16x16x32_bf16(a0l, w0h, acc[0][0], 0, 0, 0);
    acc[0][0] = __builtin_amdgcn_mfma_f32_16x16x32_bf16(a0h, w0l, acc[0][0], 0, 0, 0);
    acc[0][1] = __builtin_amdgcn_mfma_f32_16x16x32_bf16(a0h, w1h, acc[0][1], 0, 0, 0);
    acc[0][1] = __builtin_amdgcn_mfma_f32_16x16x32_bf16(a0l, w1h, acc[0][1], 0, 0, 0);
    acc[0][1] = __builtin_amdgcn_mfma_f32_16x16x32_bf16(a0h, w1l, acc[0][1], 0, 0, 0);
    acc[1][0] = __builtin_amdgcn_mfma_f32_16x16x32_bf16(a1h, w0h, acc[1][0], 0, 0, 0);
    acc[1][0] = __builtin_amdgcn_mfma_f32_16x16x32_bf16(a1l, w0h, acc[1][0], 0, 0, 0);
    acc[1][0] = __builtin_amdgcn_mfma_f32_16x16x32_bf16(a1h, w0l, acc[1][0], 0, 0, 0);
    acc[1][1] = __builtin_amdgcn_mfma_f32_16x16x32_bf16(a1h, w1h, acc[1][1], 0, 0, 0);
    acc[1][1] = __builtin_amdgcn_mfma_f32_16x16x32_bf16(a1l, w1h, acc[1][1], 0, 0, 0);
    acc[1][1] = __builtin_amdgcn_mfma_f32_16x16x32_bf16(a1h, w1l, acc[1][1], 0, 0, 0);
  }
  int dr = (l >> 4) << 2;
  #pragma unroll
  for (int mt = 0; mt < 2; mt++){
    #pragma unroll
    for (int r = 0; r < 4; r++){
      int m = mw + mt*16 + dr + r;
      if (m >= M) continue;
      #pragma unroll
      for (int nt = 0; nt < 2; nt++){
        int jj = nw + nt*16 + lm;
        float v = acc[mt][nt][r];
        if (HASB) v += bias[jj];
        if (ACT == 1) v = fmaxf(v, 0.f);
        if (MODE_C == 1){
          int b3 = m / NTOK, n = m - b3*NTOK;
          int rr = n / 28, cc = n - rr*28;
          int wo = ((rr/7)*4 + (cc/7))*WS + (rr%7)*7 + (cc%7);
          float* Cx = (jj < 256) ? C0 : ((jj < 512) ? C1 : C2);
          Cx[((size_t)(b3*NTOK + wo))*DM + (jj & 255)] = v;
        } else {
          C0[(size_t)m*(size_t)NN + jj] = v;
        }
      }
    }
  }
}

// ---- phase 2: window means (32 vblocks) ----
__device__ __forceinline__ void ph_means(int vb, const float* __restrict__ q, const float* __restrict__ k,
    const float* __restrict__ v, float* __restrict__ qm, float* __restrict__ km, float* __restrict__ vm){
  int b = vb >> 4, w = vb & 15;
  int t = threadIdx.x;
  size_t base = ((size_t)b*NTOK + w*WS)*DM + t;
  float sq=0.f, sk=0.f, sv=0.f;
  for (int p=0;p<WS;p++){ sq += q[base + (size_t)p*DM]; sk += k[base + (size_t)p*DM]; sv += v[base + (size_t)p*DM]; }
  size_t o = ((size_t)b*NW + w)*DM + t;
  qm[o]=sq*(1.f/49.f); km[o]=sk*(1.f/49.f); vm[o]=sv*(1.f/49.f);
}

// ---- phase 3: sim + top-8 + multiplicity (2 vblocks) ----
__device__ __forceinline__ void ph_topk(int b, Smem& sm, const float* __restrict__ qm,
    const float* __restrict__ km, int* __restrict__ cnt){
  int t = threadIdx.x;
  {
    int wq = t >> 4, wk = t & 15;
    const float* qp = qm + ((size_t)b*NW + wq)*DM;
    const float* kp = km + ((size_t)b*NW + wk)*DM;
    float d0=0,d1=0,d2=0,d3=0;
    for (int i=0;i<DM;i+=4){
      d0=fmaf(qp[i+0],kp[i+0],d0); d1=fmaf(qp[i+1],kp[i+1],d1);
      d2=fmaf(qp[i+2],kp[i+2],d2); d3=fmaf(qp[i+3],kp[i+3],d3);
    }
    sm.t.sim[wq][wk] = (d0+d1)+(d2+d3);
  }
  __syncthreads();
  if (t < 16){
    float vals[16];
    #pragma unroll
    for (int i=0;i<16;i++) vals[i]=sm.t.sim[t][i];
    for (int s=0;s<KTOP;s++){
      int best=0; float bv=vals[0];
      for (int i=1;i<16;i++) if (vals[i] > bv){ bv=vals[i]; best=i; }
      sm.t.sidx[t][s] = best;
      vals[best] = -1e30f;
    }
  }
  __syncthreads();
  if (t < 16){
    int c = 0;
    const int* si = &sm.t.sidx[0][0];
    #pragma unroll 8
    for (int j=0;j<NW*KTOP;j++) c += (si[j] == t) ? 1 : 0;
    cnt[b*NW + t] = c;
  }
  __syncthreads();
}

// ---- phase 4: MFMA dedup attention (208 vblocks, verified r5) ----
__device__ __forceinline__ void ph_attn(int vb, Smem& sm, const float* __restrict__ q,
    const float* __restrict__ kb, const float* __restrict__ vb_, const float* __restrict__ km,
    const float* __restrict__ vm, const int* __restrict__ cnt,
    unsigned short* __restrict__ mh, unsigned short* __restrict__ ml){
  int qt = vb % 13;
  int bh = vb / 13;
  int b = bh >> 3, h = bh & 7;
  int t = threadIdx.x;
  int w = t >> 6, l = t & 63;
  int lg = l >> 4, lm = l & 15;
  const float scale = 0.17677669529663687f;

  for (int s = t; s < 800; s += 256)
    sm.a.Wt[s] = (s < NTOK) ? (float)cnt[b*NW + s/WS] : 16.0f;

  bhalf8 qa;
  {
    int qrow = qt*64 + w*16 + lm;
    int qr = (qrow < NTOK) ? qrow : 0;
    const float* qp = q + ((size_t)(b*NTOK + qr))*DM + h*DH + lg*8;
    float4 f0 = *(const float4*)qp;
    float4 f1 = *(const float4*)(qp + 4);
    qa[0]=(short)f2b(f0.x); qa[1]=(short)f2b(f0.y); qa[2]=(short)f2b(f0.z); qa[3]=(short)f2b(f0.w);
    qa[4]=(short)f2b(f1.x); qa[5]=(short)f2b(f1.y); qa[6]=(short)f2b(f1.z); qa[7]=(short)f2b(f1.w);
  }

  floatx4 o0 = {0.f,0.f,0.f,0.f}, o1 = {0.f,0.f,0.f,0.f};
  float rs[4] = {0.f,0.f,0.f,0.f};

  auto stage = [&](int c, int buf){
    if (t < 128){
      int T = t >> 6, sl = t & 63;
      int s = c*32 + T*16 + (sl & 15);
      const float* rp = ((s < NTOK) ? (kb + ((size_t)(b*NTOK + s))*DM)
                                    : (km + ((size_t)(b*NW + (s - NTOK)))*DM)) + h*DH + (sl >> 4)*8;
      float4 f0 = *(const float4*)rp;
      float4 f1 = *(const float4*)(rp + 4);
      unsigned p0 = (unsigned)f2b(f0.x) | ((unsigned)f2b(f0.y) << 16);
      unsigned p1 = (unsigned)f2b(f0.z) | ((unsigned)f2b(f0.w) << 16);
      unsigned p2 = (unsigned)f2b(f1.x) | ((unsigned)f2b(f1.y) << 16);
      unsigned p3 = (unsigned)f2b(f1.z) | ((unsigned)f2b(f1.w) << 16);
      *(uint4*)&sm.a.Kf[buf][T*64 + sl][0] = make_uint4(p0,p1,p2,p3);
    } else {
      int tt = t - 128;
      int Td = tt >> 6, sl = tt & 63;
      int dmv = h*DH + Td*16 + (sl & 15);
      int s0 = c*32 + (sl >> 4)*8;
      unsigned pk[4];
      #pragma unroll
      for (int jj = 0; jj < 4; jj++){
        int sa = s0 + 2*jj, sb2 = s0 + 2*jj + 1;
        float fa = ((sa < NTOK) ? vb_[((size_t)(b*NTOK + sa))*DM + dmv] : vm[((size_t)(b*NW + (sa-NTOK)))*DM + dmv]);
        float fb = ((sb2 < NTOK) ? vb_[((size_t)(b*NTOK + sb2))*DM + dmv] : vm[((size_t)(b*NW + (sb2-NTOK)))*DM + dmv]);
        pk[jj] = (unsigned)f2b(fa) | ((unsigned)f2b(fb) << 16);
      }
      *(uint4*)&sm.a.Vf[buf][Td*64 + sl][0] = make_uint4(pk[0],pk[1],pk[2],pk[3]);
    }
  };

  stage(0, 0);
  __syncthreads();

  for (int c = 0; c < 25; c++){
    int buf = c & 1;
    if (c + 1 < 25) stage(c + 1, buf ^ 1);

    bhalf8 k0 = *(const bhalf8*)&sm.a.Kf[buf][l][0];
    bhalf8 k1 = *(const bhalf8*)&sm.a.Kf[buf][64 + l][0];
    floatx4 z = {0.f,0.f,0.f,0.f};
    floatx4 s0 = __builtin_amdgcn_mfma_f32_16x16x32_bf16(qa, k0, z, 0, 0, 0);
    floatx4 s1 = __builtin_amdgcn_mfma_f32_16x16x32_bf16(qa, k1, z, 0, 0, 0);
    float w0 = sm.a.Wt[c*32 + lm];
    float w1 = sm.a.Wt[c*32 + 16 + lm];
    #pragma unroll
    for (int r = 0; r < 4; r++){
      float p0 = w0 * __expf(s0[r] * scale);
      float p1 = w1 * __expf(s1[r] * scale);
      unsigned short pb0 = f2b(p0), pb1 = f2b(p1);
      rs[r] += b2f(pb0) + b2f(pb1);
      sm.a.Pl[w][lg*4 + r][lm] = (short)pb0;
      sm.a.Pl[w][lg*4 + r][16 + lm] = (short)pb1;
    }
    bhalf8 pa = *(const bhalf8*)&sm.a.Pl[w][lm][lg*8];
    bhalf8 v0 = *(const bhalf8*)&sm.a.Vf[buf][l][0];
    bhalf8 v1 = *(const bhalf8*)&sm.a.Vf[buf][64 + l][0];
    o0 = __builtin_amdgcn_mfma_f32_16x16x32_bf16(pa, v0, o0, 0, 0, 0);
    o1 = __builtin_amdgcn_mfma_f32_16x16x32_bf16(pa, v1, o1, 0, 0, 0);

    __syncthreads();
  }

  #pragma unroll
  for (int r = 0; r < 4; r++){
    float v = rs[r];
    v += __shfl_xor(v, 1); v += __shfl_xor(v, 2);
    v += __shfl_xor(v, 4); v += __shfl_xor(v, 8);
    rs[r] = v;
  }
  #pragma unroll
  for (int r = 0; r < 4; r++){
    int qq = qt*64 + w*16 + lg*4 + r;
    if (qq < NTOK){
      float inv = 1.f / rs[r];
      size_t off = ((size_t)(b*NTOK + qq))*DM + h*DH;
      unsigned short hh, ll2;
      split2(o0[r] * inv, &hh, &ll2);
      mh[off + lm] = hh; ml[off + lm] = ll2;
      split2(o1[r] * inv, &hh, &ll2);
      mh[off + 16 + lm] = hh; ml[off + 16 + lm] = ll2;
    }
  }
}

// ---- fused GEMM + LayerNorm tile (16 rows, verified r7) ----
template<int K, bool HASB, int OUT>
__device__ __forceinline__ void gln_tile(int vb, Smem& sm,
    const unsigned short* __restrict__ Ah, const unsigned short* __restrict__ Al,
    const unsigned short* __restrict__ Wh, const unsigned short* __restrict__ Wl,
    const float* __restrict__ bias, const float* __restrict__ gg, const float* __restrict__ bb,
    const float* __restrict__ xf,
    unsigned short* __restrict__ oh, unsigned short* __restrict__ ol, float* __restrict__ outp){
  int m0 = vb * 16;
  int t = threadIdx.x, w = t >> 6, l = t & 63;
  int lm = l & 15, lg = l >> 4;
  floatx4 acc[4] = {};
  int arow = m0 + lm;
  #pragma unroll 2
  for (int k0 = 0; k0 < K; k0 += 32){
    int ak = k0 + lg*8;
    bhalf8 ah = *(const bhalf8*)(Ah + (size_t)arow*K + ak);
    bhalf8 al = *(const bhalf8*)(Al + (size_t)arow*K + ak);
    #pragma unroll
    for (int ct = 0; ct < 4; ct++){
      int n = w*64 + ct*16 + lm;
      bhalf8 wh_ = *(const bhalf8*)(Wh + (size_t)n*K + ak);
      bhalf8 wl_ = *(const bhalf8*)(Wl + (size_t)n*K + ak);
      acc[ct] = __builtin_amdgcn_mfma_f32_16x16x32_bf16(ah, wh_, acc[ct], 0, 0, 0);
      acc[ct] = __builtin_amdgcn_mfma_f32_16x16x32_bf16(al, wh_, acc[ct], 0, 0, 0);
      acc[ct] = __builtin_amdgcn_mfma_f32_16x16x32_bf16(ah, wl_, acc[ct], 0, 0, 0);
    }
  }
  float s1[4] = {0.f,0.f,0.f,0.f}, s2[4] = {0.f,0.f,0.f,0.f};
  #pragma unroll
  for (int ct = 0; ct < 4; ct++){
    float bv = HASB ? bias[w*64 + ct*16 + lm] : 0.f;
    #pragma unroll
    for (int r = 0; r < 4; r++){
      float v = acc[ct][r] + bv;
      sm.g.Cs[lg*4 + r][w*64 + ct*16 + lm] = v;
      s1[r] += v; s2[r] += v*v;
    }
  }
  #pragma unroll
  for (int r = 0; r < 4; r++){
    #pragma unroll
    for (int mk = 1; mk < 16; mk <<= 1){
      s1[r] += __shfl_xor(s1[r], mk);
      s2[r] += __shfl_xor(s2[r], mk);
    }
  }
  if (lm == 0){
    #pragma unroll
    for (int r = 0; r < 4; r++){ sm.g.wps[w][lg*4+r] = s1[r]; sm.g.wpq[w][lg*4+r] = s2[r]; }
  }
  __syncthreads();
  if (t < 16){
    float a = sm.g.wps[0][t]+sm.g.wps[1][t]+sm.g.wps[2][t]+sm.g.wps[3][t];
    float qq = sm.g.wpq[0][t]+sm.g.wpq[1][t]+sm.g.wpq[2][t]+sm.g.wpq[3][t];
    float mu = a * (1.f/DM);
    float var = qq * (1.f/DM) - mu*mu;
    sm.g.smu[t] = mu; sm.g.srs[t] = rsqrtf(var + 1e-5f);
  }
  __syncthreads();
  if (OUT == 0){
    float g = gg[t], bv2 = bb[t];
    #pragma unroll
    for (int rr = 0; rr < 16; rr++){
      int m = m0 + rr;
      float o = (sm.g.Cs[rr][t] - sm.g.smu[rr]) * sm.g.srs[rr] * g + bv2;
      unsigned short hh, ll2; split2(o, &hh, &ll2);
      oh[(size_t)m*DM + t] = hh; ol[(size_t)m*DM + t] = ll2;
    }
    __syncthreads();
  } else {
    float g = gg[t], bv2 = bb[t];
    #pragma unroll
    for (int rr = 0; rr < 16; rr++){
      int m = m0 + rr;
      sm.g.Cs[rr][t] = (sm.g.Cs[rr][t] - sm.g.smu[rr]) * sm.g.srs[rr] * g + bv2 + xf[(size_t)m*DM + t];
    }
    __syncthreads();
    int r3 = t & 15;
    int d0 = (t >> 4) * 16;
    int m = m0 + r3;
    int b2 = (m < NTOK) ? 0 : 1;
    int n2 = m - b2*NTOK;
    #pragma unroll
    for (int dd = 0; dd < 16; dd++){
      int d = d0 + dd;
      outp[((size_t)(b2*DM + d))*NTOK + n2] = sm.g.Cs[r3][d];
    }
    __syncthreads();
  }
}

// ---- phase 7: depthwise conv 3x3 + gelu (1568 vblocks) ----
__device__ __forceinline__ void ph_dwconv(int m, const float* __restrict__ y1, const float* __restrict__ w,
    const float* __restrict__ bias, unsigned short* __restrict__ gh, unsigned short* __restrict__ gl){
  int b = m / NTOK, n = m - b*NTOK;
  int r = n / 28, c = n - r*28;
  for (int ch = threadIdx.x; ch < 512; ch += 256){
    float acc = bias[ch];
    #pragma unroll
    for (int ky=-1; ky<=1; ky++){
      int rr = r + ky;
      if (rr < 0 || rr >= 28) continue;
      #pragma unroll
      for (int kx=-1; kx<=1; kx++){
        int cc = c + kx;
        if (cc < 0 || cc >= 28) continue;
        acc = fmaf(y1[((size_t)b*NTOK + rr*28+cc)*512 + ch], w[ch*9 + (ky+1)*3 + (kx+1)], acc);
      }
    }
    float x = acc;
    float ge = 0.5f*x*(1.f + erff(x*0.70710678118654752f));
    unsigned short hh, ll2; split2(ge, &hh, &ll2);
    gh[(size_t)m*512 + ch] = hh; gl[(size_t)m*512 + ch] = ll2;
  }
}

// ---- the mega-kernel: 9 phases, 8 grid barriers, 256 persistent blocks ----
__global__ __launch_bounds__(256, 1) void k_mega(
    const float* __restrict__ x,
    const float* __restrict__ Wq, const float* __restrict__ Wk, const float* __restrict__ Wv,
    const float* __restrict__ Wm, const float* __restrict__ ln1g, const float* __restrict__ ln1b,
    const float* __restrict__ fc1w, const float* __restrict__ fc1b,
    const float* __restrict__ dww, const float* __restrict__ dwb,
    const float* __restrict__ fc2w, const float* __restrict__ fc2b,
    const float* __restrict__ ln2g, const float* __restrict__ ln2b,
    float* __restrict__ ws, float* __restrict__ out, int* __restrict__ bars){
  __shared__ Smem sm;
  int bid = blockIdx.x;

  float* xf = ws + O_XF;
  unsigned short* xh = (unsigned short*)(ws + O_XH);
  unsigned short* xl = (unsigned short*)(ws + O_XL);
  float* qb = ws + O_Q;
  float* kb = ws + O_K;
  float* vb = ws + O_V;
  float* qm = ws + O_QM;
  float* km = ws + O_KM;
  float* vm = ws + O_VM;
  int*   cnt = (int*)(ws + O_CNT);
  unsigned short* whi = (unsigned short*)(ws + O_WHI);
  unsigned short* wlo = (unsigned short*)(ws + O_WLO);
  unsigned short* mhp = (unsigned short*)(ws + O_MH);
  unsigned short* mlp = (unsigned short*)(ws + O_ML);
  unsigned short* m2h = (unsigned short*)(ws + O_M2H);
  unsigned short* m2l = (unsigned short*)(ws + O_M2L);
  float* y1 = ws + O_Y1;
  unsigned short* gh = (unsigned short*)(ws + O_GH);
  unsigned short* gl = (unsigned short*)(ws + O_GL);
  unsigned short* wqkv_h = whi,        *wqkv_l = wlo;
  unsigned short* wm_h   = whi+196608, *wm_l   = wlo+196608;
  unsigned short* w1_h   = whi+262144, *w1_l   = wlo+262144;
  unsigned short* w2_h   = whi+524288, *w2_l   = wlo+524288;

  // P0: prep
  for (int vbk = bid; vbk < 1040; vbk += NBLK)
    ph_prep(vbk, sm, x, xf, xh, xl, Wq, Wk, Wv, Wm, fc1w, fc2w, whi, wlo);
  gsync(bars, 0);
  // P1: qkv GEMM (300 tiles)
  for (int vbk = bid; vbk < 300; vbk += NBLK){
    int bx = vbk % 25, by = vbk / 25;
    mgemm_tile<256,0,0,false,1>(bx, by, xh, xl, nullptr, nullptr, wqkv_h, wqkv_l, nullptr,
                                qb, kb, vb, MTOT, 768);
  }
  gsync(bars, 1);
  // P2: window means (32)
  if (bid < 32) ph_means(bid, qb, kb, vb, qm, km, vm);
  gsync(bars, 2);
  // P3: topk + cnt (2)
  if (bid < 2) ph_topk(bid, sm, qm, km, cnt);
  gsync(bars, 3);
  // P4: attention (208)
  if (bid < 208) ph_attn(bid, sm, qb, kb, vb, km, vm, cnt, mhp, mlp);
  gsync(bars, 4);
  // P5: Wm + LN1 (98)
  if (bid < 98) gln_tile<256,false,0>(bid, sm, mhp, mlp, wm_h, wm_l, nullptr, ln1g, ln1b,
                                      nullptr, m2h, m2l, nullptr);
  gsync(bars, 5);
  // P6: fc1 GEMM (200 tiles)
  if (bid < 200){
    int bx = bid % 25, by = bid / 25;
    mgemm_tile<512,1,1,true,0>(bx, by, xh, xl, m2h, m2l, w1_h, w1_l, fc1b,
                               y1, nullptr, nullptr, MTOT, 512);
  }
  gsync(bars, 6);
  // P7: dwconv + gelu (1568)
  for (int vbk = bid; vbk < MTOT; vbk += NBLK)
    ph_dwconv(vbk, y1, dww, dwb, gh, gl);
  gsync(bars, 7);
  // P8: fc2 + LN2 + residual + transposed store (98)
  if (bid < 98) gln_tile<512,true,1>(bid, sm, gh, gl, w2_h, w2_l, fc2b, ln2g, ln2b,
                                     xf, nullptr, nullptr, out);
}

extern "C" void kernel_launch(void* const* d_in, const int* in_sizes, int n_in,
                              void* d_out, int out_size, void* d_ws, size_t ws_size,
                              hipStream_t stream){
  const float* x    = (const float*)d_in[0];
  const float* Wq   = (const float*)d_in[1];
  const float* Wk   = (const float*)d_in[2];
  const float* Wv   = (const float*)d_in[3];
  const float* Wm   = (const float*)d_in[4];
  const float* ln1g = (const float*)d_in[5];
  const float* ln1b = (const float*)d_in[6];
  const float* fc1w = (const float*)d_in[7];
  const float* fc1b = (const float*)d_in[8];
  const float* dww  = (const float*)d_in[9];
  const float* dwb  = (const float*)d_in[10];
  const float* fc2w = (const float*)d_in[11];
  const float* fc2b = (const float*)d_in[12];
  const float* ln2g = (const float*)d_in[13];
  const float* ln2b = (const float*)d_in[14];

  float* ws  = (float*)d_ws;
  float* out = (float*)d_out;
  int* bars  = (int*)(ws + O_BAR);

  k_zero<<<1, 64, 0, stream>>>(bars);
  k_mega<<<NBLK, 256, 0, stream>>>(x, Wq, Wk, Wv, Wm, ln1g, ln1b, fc1w, fc1b,
                                   dww, dwb, fc2w, fc2b, ln2g, ln2b, ws, out, bars);
}

// Round 9
// 218.161 us; speedup vs baseline: 1.8783x; 1.8783x over previous
//
#include <hip/hip_runtime.h>
#include <math.h>

#define BB 2
#define NTOK 784
#define DM 256
#define NH 8
#define DH 32
#define NW 16
#define WS 49
#define KTOP 8
#define MTOT 1568

// ---- workspace offsets (float units) ----
#define O_XF    0
#define O_XH    401408
#define O_XL    602112
#define O_Q     802816
#define O_K     1204224
#define O_V     1605632
#define O_QM    2007040
#define O_KM    2015232
#define O_VM    2023424
#define O_CTR   2031616
#define O_CNT   2031680
#define O_WHI   2031936
#define O_WLO   2359616
#define O_MH    2687296
#define O_ML    2888000
#define O_Y1A   3088704
#define O_Y1    3891520
#define O_GH    4694336
#define O_GL    5095744
// total 5497152 floats = 22.0 MB

typedef __attribute__((ext_vector_type(8))) short bhalf8;
typedef __attribute__((ext_vector_type(4))) float floatx4;

__device__ __forceinline__ unsigned short f2b(float f){
  unsigned u = __float_as_uint(f);
  return (unsigned short)((u + 0x7fffu + ((u >> 16) & 1u)) >> 16);
}
__device__ __forceinline__ float b2f(unsigned short h){
  return __uint_as_float(((unsigned)h) << 16);
}
__device__ __forceinline__ void split2(float f, unsigned short* hi, unsigned short* lo){
  unsigned short h = f2b(f);
  *hi = h;
  *lo = f2b(f - b2f(h));
}

// ---------------- fused prep: transpose x -> xf/xh/xl | cast weights | zero counters ----
__global__ __launch_bounds__(256) void k_prep(const float* __restrict__ x, float* __restrict__ xf,
    unsigned short* __restrict__ xh, unsigned short* __restrict__ xl,
    const float* __restrict__ Wq, const float* __restrict__ Wk, const float* __restrict__ Wv,
    const float* __restrict__ Wm, const float* __restrict__ f1, const float* __restrict__ f2,
    unsigned short* __restrict__ dhi, unsigned short* __restrict__ dlo, int* __restrict__ ctr){
  int bid = blockIdx.x;
  int t = threadIdx.x;
  if (bid < 400){
    __shared__ float tile[32][33];
    int b = bid / 200; int r = bid - b*200;
    int d0 = (r / 25) * 32, n0 = (r % 25) * 32;
    int tx = t & 31, ty = t >> 5;
    #pragma unroll
    for (int i = 0; i < 4; i++){
      int d = d0 + ty + i*8, n = n0 + tx;
      if (n < NTOK) tile[ty + i*8][tx] = x[((size_t)b*DM + d)*NTOK + n];
    }
    __syncthreads();
    #pragma unroll
    for (int i = 0; i < 4; i++){
      int n = n0 + ty + i*8, d = d0 + tx;
      if (n < NTOK){
        float v = tile[tx][ty + i*8];
        size_t o = ((size_t)b*NTOK + n)*DM + d;
        xf[o] = v;
        unsigned short h, l; split2(v, &h, &l);
        xh[o] = h; xl[o] = l;
      }
    }
  } else {
    if (bid == 400 && t < 4) ctr[t] = 0;
    int i = ((bid - 400)*256 + t)*4;
    const float* src; int off;
    if (i < 65536){ src=Wq; off=i; }
    else if (i < 131072){ src=Wk; off=i-65536; }
    else if (i < 196608){ src=Wv; off=i-131072; }
    else if (i < 262144){ src=Wm; off=i-196608; }
    else if (i < 524288){ src=f1; off=i-262144; }
    else { src=f2; off=i-524288; }
    float4 fv = *(const float4*)(src + off);
    ushort4 oh, ol;
    split2(fv.x, &oh.x, &ol.x);
    split2(fv.y, &oh.y, &ol.y);
    split2(fv.z, &oh.z, &ol.z);
    split2(fv.w, &oh.w, &ol.w);
    *(ushort4*)(dhi + i) = oh;
    *(ushort4*)(dlo + i) = ol;
  }
}

// ---- split-bf16 MFMA GEMM tile (r4-verified layout); WST = W row stride (K-loop is 256) ----
template<int WST, int ACT, bool HASB, int MODE_C>
__device__ __forceinline__ void mgemm_tile(int bx, int by,
    const unsigned short* __restrict__ Ah0, const unsigned short* __restrict__ Al0,
    const unsigned short* __restrict__ Wh, const unsigned short* __restrict__ Wl,
    const float* __restrict__ bias,
    float* __restrict__ C0, float* __restrict__ C1, float* __restrict__ C2,
    int M, int NN){
  int t = threadIdx.x;
  int w = t >> 6, l = t & 63;
  int lm = l & 15;
  int lk = (l >> 4) << 3;
  int mw = bx * 64 + (w >> 1) * 32;
  int nw = by * 64 + (w & 1) * 32;
  floatx4 acc[2][2] = {};
  int ar0 = mw + lm, ar1 = ar0 + 16;
  int ga0 = (ar0 < M) ? ar0 : 0;
  int ga1 = (ar1 < M) ? ar1 : 0;
  int nr0 = nw + lm, nr1 = nr0 + 16;
  #pragma unroll 4
  for (int k0 = 0; k0 < 256; k0 += 32){
    int ak = k0 + lk;
    bhalf8 a0h = *(const bhalf8*)(Ah0 + (size_t)ga0*256 + ak);
    bhalf8 a0l = *(const bhalf8*)(Al0 + (size_t)ga0*256 + ak);
    bhalf8 a1h = *(const bhalf8*)(Ah0 + (size_t)ga1*256 + ak);
    bhalf8 a1l = *(const bhalf8*)(Al0 + (size_t)ga1*256 + ak);
    bhalf8 w0h = *(const bhalf8*)(Wh + (size_t)nr0*WST + ak);
    bhalf8 w0l = *(const bhalf8*)(Wl + (size_t)nr0*WST + ak);
    bhalf8 w1h = *(const bhalf8*)(Wh + (size_t)nr1*WST + ak);
    bhalf8 w1l = *(const bhalf8*)(Wl + (size_t)nr1*WST + ak);
    acc[0][0] = __builtin_amdgcn_mfma_f32_16x16x32_bf16(a0h, w0h, acc[0][0], 0, 0, 0);
    acc[0][0] = __builtin_amdgcn_mfma_f32_16x16x32_bf16(a0l, w0h, acc[0][0], 0, 0, 0);
    acc[0][0] = __builtin_amdgcn_mfma_f32_16x16x32_bf16(a0h, w0l, acc[0][0], 0, 0, 0);
    acc[0][1] = __builtin_amdgcn_mfma_f32_16x16x32_bf16(a0h, w1h, acc[0][1], 0, 0, 0);
    acc[0][1] = __builtin_amdgcn_mfma_f32_16x16x32_bf16(a0l, w1h, acc[0][1], 0, 0, 0);
    acc[0][1] = __builtin_amdgcn_mfma_f32_16x16x32_bf16(a0h, w1l, acc[0][1], 0, 0, 0);
    acc[1][0] = __builtin_amdgcn_mfma_f32_16x16x32_bf16(a1h, w0h, acc[1][0], 0, 0, 0);
    acc[1][0] = __builtin_amdgcn_mfma_f32_16x16x32_bf16(a1l, w0h, acc[1][0], 0, 0, 0);
    acc[1][0] = __builtin_amdgcn_mfma_f32_16x16x32_bf16(a1h, w0l, acc[1][0], 0, 0, 0);
    acc[1][1] = __builtin_amdgcn_mfma_f32_16x16x32_bf16(a1h, w1h, acc[1][1], 0, 0, 0);
    acc[1][1] = __builtin_amdgcn_mfma_f32_16x16x32_bf16(a1l, w1h, acc[1][1], 0, 0, 0);
    acc[1][1] = __builtin_amdgcn_mfma_f32_16x16x32_bf16(a1h, w1l, acc[1][1], 0, 0, 0);
  }
  int dr = (l >> 4) << 2;
  #pragma unroll
  for (int mt = 0; mt < 2; mt++){
    #pragma unroll
    for (int r = 0; r < 4; r++){
      int m = mw + mt*16 + dr + r;
      if (m >= M) continue;
      #pragma unroll
      for (int nt = 0; nt < 2; nt++){
        int jj = nw + nt*16 + lm;
        float v = acc[mt][nt][r];
        if (HASB) v += bias[jj];
        if (ACT == 1) v = fmaxf(v, 0.f);
        if (MODE_C == 1){
          int b3 = m / NTOK, n = m - b3*NTOK;
          int rr = n / 28, cc = n - rr*28;
          int wo = ((rr/7)*4 + (cc/7))*WS + (rr%7)*7 + (cc%7);
          float* Cx = (jj < 256) ? C0 : ((jj < 512) ? C1 : C2);
          Cx[((size_t)(b3*NTOK + wo))*DM + (jj & 255)] = v;
        } else {
          C0[(size_t)m*(size_t)NN + jj] = v;
        }
      }
    }
  }
}

// qkv (by<12) + y1a = xh@W1[:, :256] + fc1b (by>=12, off critical path)
__global__ __launch_bounds__(256) void k_qkv_y1a(const unsigned short* __restrict__ Ah, const unsigned short* __restrict__ Al,
    const unsigned short* __restrict__ Wqkvh, const unsigned short* __restrict__ Wqkvl,
    const unsigned short* __restrict__ W1h, const unsigned short* __restrict__ W1l,
    const float* __restrict__ fc1b,
    float* __restrict__ q, float* __restrict__ k, float* __restrict__ v, float* __restrict__ y1a){
  if (blockIdx.y < 12){
    mgemm_tile<256,0,false,1>(blockIdx.x, blockIdx.y, Ah, Al, Wqkvh, Wqkvl, nullptr,
                              q, k, v, MTOT, 768);
  } else {
    mgemm_tile<512,0,true,0>(blockIdx.x, blockIdx.y - 12, Ah, Al, W1h, W1l, fc1b,
                             y1a, nullptr, nullptr, MTOT, 512);
  }
}

// ---------------- fused means + sim + top-8 + multiplicity (last-block tail) ----------------
__global__ __launch_bounds__(256) void k_meanstopk(const float* __restrict__ q, const float* __restrict__ k,
    const float* __restrict__ v, float* __restrict__ qm, float* __restrict__ km, float* __restrict__ vm,
    int* __restrict__ cnt, int* __restrict__ ctr){
  int b = blockIdx.x >> 4, w = blockIdx.x & 15;
  int t = threadIdx.x;
  size_t base = ((size_t)b*NTOK + w*WS)*DM + t;
  float sq=0.f, sk=0.f, sv=0.f;
  for (int p=0;p<WS;p++){ sq += q[base + (size_t)p*DM]; sk += k[base + (size_t)p*DM]; sv += v[base + (size_t)p*DM]; }
  size_t o = ((size_t)b*NW + w)*DM + t;
  qm[o]=sq*(1.f/49.f); km[o]=sk*(1.f/49.f); vm[o]=sv*(1.f/49.f);

  __threadfence();
  __shared__ int lastFlag;
  if (t == 0) lastFlag = (atomicAdd(&ctr[b], 1) == NW-1);
  __syncthreads();
  if (!lastFlag) return;
  __threadfence();

  __shared__ float sim[16][16];
  __shared__ int sidx[16][KTOP];
  {
    int wq = t >> 4, wk = t & 15;
    const float* qp = qm + ((size_t)b*NW + wq)*DM;
    const float* kp = km + ((size_t)b*NW + wk)*DM;
    float d0=0,d1=0,d2=0,d3=0;
    for (int i=0;i<DM;i+=4){
      d0=fmaf(qp[i+0],kp[i+0],d0); d1=fmaf(qp[i+1],kp[i+1],d1);
      d2=fmaf(qp[i+2],kp[i+2],d2); d3=fmaf(qp[i+3],kp[i+3],d3);
    }
    sim[wq][wk] = (d0+d1)+(d2+d3);
  }
  __syncthreads();
  if (t < 16){
    float vals[16];
    #pragma unroll
    for (int i=0;i<16;i++) vals[i]=sim[t][i];
    for (int s=0;s<KTOP;s++){
      int best=0; float bv=vals[0];
      for (int i=1;i<16;i++) if (vals[i] > bv){ bv=vals[i]; best=i; }
      sidx[t][s] = best;
      vals[best] = -1e30f;
    }
  }
  __syncthreads();
  if (t < 16){
    int c = 0;
    const int* si = &sidx[0][0];
    #pragma unroll 8
    for (int j=0;j<NW*KTOP;j++) c += (si[j] == t) ? 1 : 0;
    cnt[b*NW + t] = c;
  }
}

// ---------------- MFMA dedup attention (verified r5) ----------------
__global__ __launch_bounds__(256) void k_attn(const float* __restrict__ q,
    const float* __restrict__ kb, const float* __restrict__ vb,
    const float* __restrict__ km, const float* __restrict__ vm,
    const int* __restrict__ cnt,
    unsigned short* __restrict__ mh, unsigned short* __restrict__ ml){
  __shared__ __align__(16) short Kf[2][128][8];
  __shared__ __align__(16) short Vf[2][128][8];
  __shared__ float Wt[800];
  __shared__ __align__(16) short Pl[4][16][40];

  int qt = blockIdx.x;
  int bh = blockIdx.y;
  int b = bh >> 3, h = bh & 7;
  int t = threadIdx.x;
  int w = t >> 6, l = t & 63;
  int lg = l >> 4, lm = l & 15;
  const float scale = 0.17677669529663687f;

  for (int s = t; s < 800; s += 256)
    Wt[s] = (s < NTOK) ? (float)cnt[b*NW + s/WS] : 16.0f;

  bhalf8 qa;
  {
    int qrow = qt*64 + w*16 + lm;
    int qr = (qrow < NTOK) ? qrow : 0;
    const float* qp = q + ((size_t)(b*NTOK + qr))*DM + h*DH + lg*8;
    float4 f0 = *(const float4*)qp;
    float4 f1 = *(const float4*)(qp + 4);
    qa[0]=(short)f2b(f0.x); qa[1]=(short)f2b(f0.y); qa[2]=(short)f2b(f0.z); qa[3]=(short)f2b(f0.w);
    qa[4]=(short)f2b(f1.x); qa[5]=(short)f2b(f1.y); qa[6]=(short)f2b(f1.z); qa[7]=(short)f2b(f1.w);
  }

  floatx4 o0 = {0.f,0.f,0.f,0.f}, o1 = {0.f,0.f,0.f,0.f};
  float rs[4] = {0.f,0.f,0.f,0.f};

  auto stage = [&](int c, int buf){
    if (t < 128){
      int T = t >> 6, sl = t & 63;
      int s = c*32 + T*16 + (sl & 15);
      const float* rp = ((s < NTOK) ? (kb + ((size_t)(b*NTOK + s))*DM)
                                    : (km + ((size_t)(b*NW + (s - NTOK)))*DM)) + h*DH + (sl >> 4)*8;
      float4 f0 = *(const float4*)rp;
      float4 f1 = *(const float4*)(rp + 4);
      unsigned p0 = (unsigned)f2b(f0.x) | ((unsigned)f2b(f0.y) << 16);
      unsigned p1 = (unsigned)f2b(f0.z) | ((unsigned)f2b(f0.w) << 16);
      unsigned p2 = (unsigned)f2b(f1.x) | ((unsigned)f2b(f1.y) << 16);
      unsigned p3 = (unsigned)f2b(f1.z) | ((unsigned)f2b(f1.w) << 16);
      *(uint4*)&Kf[buf][T*64 + sl][0] = make_uint4(p0,p1,p2,p3);
    } else {
      int tt = t - 128;
      int Td = tt >> 6, sl = tt & 63;
      int dmv = h*DH + Td*16 + (sl & 15);
      int s0 = c*32 + (sl >> 4)*8;
      unsigned pk[4];
      #pragma unroll
      for (int jj = 0; jj < 4; jj++){
        int sa = s0 + 2*jj, sb2 = s0 + 2*jj + 1;
        float fa = ((sa < NTOK) ? vb[((size_t)(b*NTOK + sa))*DM + dmv] : vm[((size_t)(b*NW + (sa-NTOK)))*DM + dmv]);
        float fb = ((sb2 < NTOK) ? vb[((size_t)(b*NTOK + sb2))*DM + dmv] : vm[((size_t)(b*NW + (sb2-NTOK)))*DM + dmv]);
        pk[jj] = (unsigned)f2b(fa) | ((unsigned)f2b(fb) << 16);
      }
      *(uint4*)&Vf[buf][Td*64 + sl][0] = make_uint4(pk[0],pk[1],pk[2],pk[3]);
    }
  };

  stage(0, 0);
  __syncthreads();

  for (int c = 0; c < 25; c++){
    int buf = c & 1;
    if (c + 1 < 25) stage(c + 1, buf ^ 1);

    bhalf8 k0 = *(const bhalf8*)&Kf[buf][l][0];
    bhalf8 k1 = *(const bhalf8*)&Kf[buf][64 + l][0];
    floatx4 z = {0.f,0.f,0.f,0.f};
    floatx4 s0 = __builtin_amdgcn_mfma_f32_16x16x32_bf16(qa, k0, z, 0, 0, 0);
    floatx4 s1 = __builtin_amdgcn_mfma_f32_16x16x32_bf16(qa, k1, z, 0, 0, 0);
    float w0 = Wt[c*32 + lm];
    float w1 = Wt[c*32 + 16 + lm];
    #pragma unroll
    for (int r = 0; r < 4; r++){
      float p0 = w0 * __expf(s0[r] * scale);
      float p1 = w1 * __expf(s1[r] * scale);
      unsigned short pb0 = f2b(p0), pb1 = f2b(p1);
      rs[r] += b2f(pb0) + b2f(pb1);
      Pl[w][lg*4 + r][lm] = (short)pb0;
      Pl[w][lg*4 + r][16 + lm] = (short)pb1;
    }
    bhalf8 pa = *(const bhalf8*)&Pl[w][lm][lg*8];
    bhalf8 v0 = *(const bhalf8*)&Vf[buf][l][0];
    bhalf8 v1 = *(const bhalf8*)&Vf[buf][64 + l][0];
    o0 = __builtin_amdgcn_mfma_f32_16x16x32_bf16(pa, v0, o0, 0, 0, 0);
    o1 = __builtin_amdgcn_mfma_f32_16x16x32_bf16(pa, v1, o1, 0, 0, 0);

    __syncthreads();
  }

  #pragma unroll
  for (int r = 0; r < 4; r++){
    float v = rs[r];
    v += __shfl_xor(v, 1); v += __shfl_xor(v, 2);
    v += __shfl_xor(v, 4); v += __shfl_xor(v, 8);
    rs[r] = v;
  }
  #pragma unroll
  for (int r = 0; r < 4; r++){
    int qq = qt*64 + w*16 + lg*4 + r;
    if (qq < NTOK){
      float inv = 1.f / rs[r];
      size_t off = ((size_t)(b*NTOK + qq))*DM + h*DH;
      unsigned short hh, ll2;
      split2(o0[r] * inv, &hh, &ll2);
      mh[off + lm] = hh; ml[off + lm] = ll2;
      split2(o1[r] * inv, &hh, &ll2);
      mh[off + 16 + lm] = hh; ml[off + 16 + lm] = ll2;
    }
  }
}

// ---------------- fused Wm GEMM + LN1 + fc1b (m2 stays in LDS) -> y1 ----------------
// Block = 16 rows. Phase A: t1 = msg@Wm^T, LN -> m2 (LDS, bf16 hi/lo, frag-readable).
// Phase B: y1 = relu(y1a + m2 @ W1[:, 256:512]^T), 512 cols in 2 passes.
__global__ __launch_bounds__(256) void k_wm_fc1(const unsigned short* __restrict__ mh, const unsigned short* __restrict__ ml,
    const unsigned short* __restrict__ Wmh, const unsigned short* __restrict__ Wml,
    const unsigned short* __restrict__ W1h, const unsigned short* __restrict__ W1l,
    const float* __restrict__ gg, const float* __restrict__ bb,
    const float* __restrict__ y1a, float* __restrict__ y1){
  __shared__ __align__(16) float Cs[16][261];
  __shared__ __align__(16) short M2h[16][264], M2l[16][264];
  __shared__ float wps[4][16], wpq[4][16], smu[16], srs[16];
  int m0 = blockIdx.x * 16;
  int t = threadIdx.x, w = t >> 6, l = t & 63;
  int lm = l & 15, lg = l >> 4;

  // Phase A: Wm GEMM (K=256)
  floatx4 acc[4] = {};
  int arow = m0 + lm;
  #pragma unroll 2
  for (int k0 = 0; k0 < 256; k0 += 32){
    int ak = k0 + lg*8;
    bhalf8 ah = *(const bhalf8*)(mh + (size_t)arow*256 + ak);
    bhalf8 al = *(const bhalf8*)(ml + (size_t)arow*256 + ak);
    #pragma unroll
    for (int ct = 0; ct < 4; ct++){
      int n = w*64 + ct*16 + lm;
      bhalf8 wh_ = *(const bhalf8*)(Wmh + (size_t)n*256 + ak);
      bhalf8 wl_ = *(const bhalf8*)(Wml + (size_t)n*256 + ak);
      acc[ct] = __builtin_amdgcn_mfma_f32_16x16x32_bf16(ah, wh_, acc[ct], 0, 0, 0);
      acc[ct] = __builtin_amdgcn_mfma_f32_16x16x32_bf16(al, wh_, acc[ct], 0, 0, 0);
      acc[ct] = __builtin_amdgcn_mfma_f32_16x16x32_bf16(ah, wl_, acc[ct], 0, 0, 0);
    }
  }
  float s1[4] = {0.f,0.f,0.f,0.f}, s2[4] = {0.f,0.f,0.f,0.f};
  #pragma unroll
  for (int ct = 0; ct < 4; ct++){
    #pragma unroll
    for (int r = 0; r < 4; r++){
      float v = acc[ct][r];
      Cs[lg*4 + r][w*64 + ct*16 + lm] = v;
      s1[r] += v; s2[r] += v*v;
    }
  }
  #pragma unroll
  for (int r = 0; r < 4; r++){
    #pragma unroll
    for (int mk = 1; mk < 16; mk <<= 1){
      s1[r] += __shfl_xor(s1[r], mk);
      s2[r] += __shfl_xor(s2[r], mk);
    }
  }
  if (lm == 0){
    #pragma unroll
    for (int r = 0; r < 4; r++){ wps[w][lg*4+r] = s1[r]; wpq[w][lg*4+r] = s2[r]; }
  }
  __syncthreads();
  if (t < 16){
    float a = wps[0][t]+wps[1][t]+wps[2][t]+wps[3][t];
    float qq = wpq[0][t]+wpq[1][t]+wpq[2][t]+wpq[3][t];
    float mu = a * (1.f/DM);
    float var = qq * (1.f/DM) - mu*mu;
    smu[t] = mu; srs[t] = rsqrtf(var + 1e-5f);
  }
  __syncthreads();
  // LN -> m2 in LDS (thread t = col)
  {
    float g = gg[t], bv2 = bb[t];
    #pragma unroll
    for (int rr = 0; rr < 16; rr++){
      float o = (Cs[rr][t] - smu[rr]) * srs[rr] * g + bv2;
      unsigned short hh, ll2; split2(o, &hh, &ll2);
      M2h[rr][t] = (short)hh; M2l[rr][t] = (short)ll2;
    }
  }
  __syncthreads();

  // Phase B: fc1b, K=256 from LDS; 512 cols in 2 passes of 256
  #pragma unroll
  for (int p = 0; p < 2; p++){
    floatx4 a2[4] = {};
    #pragma unroll 2
    for (int k0 = 0; k0 < 256; k0 += 32){
      int ak = k0 + lg*8;
      bhalf8 ah2 = *(const bhalf8*)&M2h[lm][ak];
      bhalf8 al2 = *(const bhalf8*)&M2l[lm][ak];
      #pragma unroll
      for (int ct = 0; ct < 4; ct++){
        int j = p*256 + w*64 + ct*16 + lm;
        bhalf8 wh_ = *(const bhalf8*)(W1h + (size_t)j*512 + 256 + ak);
        bhalf8 wl_ = *(const bhalf8*)(W1l + (size_t)j*512 + 256 + ak);
        a2[ct] = __builtin_amdgcn_mfma_f32_16x16x32_bf16(ah2, wh_, a2[ct], 0, 0, 0);
        a2[ct] = __builtin_amdgcn_mfma_f32_16x16x32_bf16(al2, wh_, a2[ct], 0, 0, 0);
        a2[ct] = __builtin_amdgcn_mfma_f32_16x16x32_bf16(ah2, wl_, a2[ct], 0, 0, 0);
      }
    }
    #pragma unroll
    for (int ct = 0; ct < 4; ct++){
      #pragma unroll
      for (int r = 0; r < 4; r++){
        int m = m0 + lg*4 + r;
        int j = p*256 + w*64 + ct*16 + lm;
        float v = a2[ct][r] + y1a[(size_t)m*512 + j];
        y1[(size_t)m*512 + j] = fmaxf(v, 0.f);
      }
    }
  }
}

// ---------------- depthwise conv 3x3 SAME + bias + exact gelu -> hi/lo bf16 ----------------
__global__ __launch_bounds__(256) void k_dwconv(const float* __restrict__ y1, const float* __restrict__ w,
    const float* __restrict__ bias, unsigned short* __restrict__ gh, unsigned short* __restrict__ gl){
  int m = blockIdx.x;
  int b = m / NTOK, n = m - b*NTOK;
  int r = n / 28, c = n - r*28;
  for (int ch = threadIdx.x; ch < 512; ch += 256){
    float acc = bias[ch];
    #pragma unroll
    for (int ky=-1; ky<=1; ky++){
      int rr = r + ky;
      if (rr < 0 || rr >= 28) continue;
      #pragma unroll
      for (int kx=-1; kx<=1; kx++){
        int cc = c + kx;
        if (cc < 0 || cc >= 28) continue;
        acc = fmaf(y1[((size_t)b*NTOK + rr*28+cc)*512 + ch], w[ch*9 + (ky+1)*3 + (kx+1)], acc);
      }
    }
    float x = acc;
    float ge = 0.5f*x*(1.f + erff(x*0.70710678118654752f));
    unsigned short hh, ll2; split2(ge, &hh, &ll2);
    gh[(size_t)m*512 + ch] = hh; gl[(size_t)m*512 + ch] = ll2;
  }
}

// ---------------- fused fc2 GEMM + bias + LN2 + residual + transposed store (r7-verified) ----
__global__ __launch_bounds__(256) void k_fc2_ln2(const unsigned short* __restrict__ gh, const unsigned short* __restrict__ gl,
    const unsigned short* __restrict__ Wh, const unsigned short* __restrict__ Wl,
    const float* __restrict__ bias, const float* __restrict__ gg, const float* __restrict__ bb,
    const float* __restrict__ xf, float* __restrict__ out){
  __shared__ __align__(16) float Cs[16][261];
  __shared__ float wps[4][16], wpq[4][16], smu[16], srs[16];
  int m0 = blockIdx.x * 16;
  int t = threadIdx.x, w = t >> 6, l = t & 63;
  int lm = l & 15, lg = l >> 4;
  floatx4 acc[4] = {};
  int arow = m0 + lm;
  #pragma unroll 2
  for (int k0 = 0; k0 < 512; k0 += 32){
    int ak = k0 + lg*8;
    bhalf8 ah = *(const bhalf8*)(gh + (size_t)arow*512 + ak);
    bhalf8 al = *(const bhalf8*)(gl + (size_t)arow*512 + ak);
    #pragma unroll
    for (int ct = 0; ct < 4; ct++){
      int n = w*64 + ct*16 + lm;
      bhalf8 wh_ = *(const bhalf8*)(Wh + (size_t)n*512 + ak);
      bhalf8 wl_ = *(const bhalf8*)(Wl + (size_t)n*512 + ak);
      acc[ct] = __builtin_amdgcn_mfma_f32_16x16x32_bf16(ah, wh_, acc[ct], 0, 0, 0);
      acc[ct] = __builtin_amdgcn_mfma_f32_16x16x32_bf16(al, wh_, acc[ct], 0, 0, 0);
      acc[ct] = __builtin_amdgcn_mfma_f32_16x16x32_bf16(ah, wl_, acc[ct], 0, 0, 0);
    }
  }
  float s1[4] = {0.f,0.f,0.f,0.f}, s2[4] = {0.f,0.f,0.f,0.f};
  #pragma unroll
  for (int ct = 0; ct < 4; ct++){
    float bv = bias[w*64 + ct*16 + lm];
    #pragma unroll
    for (int r = 0; r < 4; r++){
      float v = acc[ct][r] + bv;
      Cs[lg*4 + r][w*64 + ct*16 + lm] = v;
      s1[r] += v; s2[r] += v*v;
    }
  }
  #pragma unroll
  for (int r = 0; r < 4; r++){
    #pragma unroll
    for (int mk = 1; mk < 16; mk <<= 1){
      s1[r] += __shfl_xor(s1[r], mk);
      s2[r] += __shfl_xor(s2[r], mk);
    }
  }
  if (lm == 0){
    #pragma unroll
    for (int r = 0; r < 4; r++){ wps[w][lg*4+r] = s1[r]; wpq[w][lg*4+r] = s2[r]; }
  }
  __syncthreads();
  if (t < 16){
    float a = wps[0][t]+wps[1][t]+wps[2][t]+wps[3][t];
    float qq = wpq[0][t]+wpq[1][t]+wpq[2][t]+wpq[3][t];
    float mu = a * (1.f/DM);
    float var = qq * (1.f/DM) - mu*mu;
    smu[t] = mu; srs[t] = rsqrtf(var + 1e-5f);
  }
  __syncthreads();
  {
    float g = gg[t], bv2 = bb[t];
    #pragma unroll
    for (int rr = 0; rr < 16; rr++){
      int m = m0 + rr;
      Cs[rr][t] = (Cs[rr][t] - smu[rr]) * srs[rr] * g + bv2 + xf[(size_t)m*DM + t];
    }
  }
  __syncthreads();
  {
    int r3 = t & 15;
    int d0 = (t >> 4) * 16;
    int m = m0 + r3;
    int b2 = (m < NTOK) ? 0 : 1;
    int n2 = m - b2*NTOK;
    #pragma unroll
    for (int dd = 0; dd < 16; dd++){
      int d = d0 + dd;
      out[((size_t)(b2*DM + d))*NTOK + n2] = Cs[r3][d];
    }
  }
}

extern "C" void kernel_launch(void* const* d_in, const int* in_sizes, int n_in,
                              void* d_out, int out_size, void* d_ws, size_t ws_size,
                              hipStream_t stream){
  const float* x    = (const float*)d_in[0];
  const float* Wq   = (const float*)d_in[1];
  const float* Wk   = (const float*)d_in[2];
  const float* Wv   = (const float*)d_in[3];
  const float* Wm   = (const float*)d_in[4];
  const float* ln1g = (const float*)d_in[5];
  const float* ln1b = (const float*)d_in[6];
  const float* fc1w = (const float*)d_in[7];
  const float* fc1b = (const float*)d_in[8];
  const float* dww  = (const float*)d_in[9];
  const float* dwb  = (const float*)d_in[10];
  const float* fc2w = (const float*)d_in[11];
  const float* fc2b = (const float*)d_in[12];
  const float* ln2g = (const float*)d_in[13];
  const float* ln2b = (const float*)d_in[14];

  float* ws  = (float*)d_ws;
  float* out = (float*)d_out;
  float* xf   = ws + O_XF;
  unsigned short* xh = (unsigned short*)(ws + O_XH);
  unsigned short* xl = (unsigned short*)(ws + O_XL);
  float* qb   = ws + O_Q;
  float* kb   = ws + O_K;
  float* vb   = ws + O_V;
  float* qm   = ws + O_QM;
  float* km   = ws + O_KM;
  float* vm   = ws + O_VM;
  int*   ctr  = (int*)(ws + O_CTR);
  int*   cnt  = (int*)(ws + O_CNT);
  unsigned short* whi = (unsigned short*)(ws + O_WHI);
  unsigned short* wlo = (unsigned short*)(ws + O_WLO);
  unsigned short* mhp = (unsigned short*)(ws + O_MH);
  unsigned short* mlp = (unsigned short*)(ws + O_ML);
  float* y1a  = ws + O_Y1A;
  float* y1   = ws + O_Y1;
  unsigned short* gh  = (unsigned short*)(ws + O_GH);
  unsigned short* gl  = (unsigned short*)(ws + O_GL);

  unsigned short* wqkv_h = whi,        *wqkv_l = wlo;
  unsigned short* wm_h   = whi+196608, *wm_l   = wlo+196608;
  unsigned short* w1_h   = whi+262144, *w1_l   = wlo+262144;
  unsigned short* w2_h   = whi+524288, *w2_l   = wlo+524288;

  k_prep<<<1040, 256, 0, stream>>>(x, xf, xh, xl, Wq, Wk, Wv, Wm, fc1w, fc2w, whi, wlo, ctr);
  k_qkv_y1a<<<dim3(25,20), 256, 0, stream>>>(xh, xl, wqkv_h, wqkv_l, w1_h, w1_l, fc1b, qb, kb, vb, y1a);
  k_meanstopk<<<BB*NW, 256, 0, stream>>>(qb, kb, vb, qm, km, vm, cnt, ctr);
  k_attn<<<dim3(13,16), 256, 0, stream>>>(qb, kb, vb, km, vm, cnt, mhp, mlp);
  k_wm_fc1<<<98, 256, 0, stream>>>(mhp, mlp, wm_h, wm_l, w1_h, w1_l, ln1g, ln1b, y1a, y1);
  k_dwconv<<<MTOT, 256, 0, stream>>>(y1, dww, dwb, gh, gl);
  k_fc2_ln2<<<98, 256, 0, stream>>>(gh, gl, w2_h, w2_l, fc2b, ln2g, ln2b, xf, out);
}

// Round 10
// 200.975 us; speedup vs baseline: 2.0389x; 1.0855x over previous
//
#include <hip/hip_runtime.h>
#include <math.h>

#define BB 2
#define NTOK 784
#define DM 256
#define NH 8
#define DH 32
#define NW 16
#define WS 49
#define KTOP 8
#define MTOT 1568

// ---- workspace offsets (float units) ----
#define O_XF    0
#define O_XH    401408
#define O_XL    602112
#define O_Q     802816
#define O_K     1204224
#define O_V     1605632
#define O_QB    2007040
#define O_KB    2207744
#define O_VT    2412544
#define O_QM    2617344
#define O_KM    2625536
#define O_VM    2633728
#define O_CTR   2641920
#define O_CNT   2641936
#define O_WHI   2642000
#define O_WLO   2969680
#define O_MH    3297360
#define O_ML    3498064
#define O_Y1A   3698768
#define O_Y1    4501584
#define O_GH    5304400
#define O_GL    5705808
// total 6107216 floats = 24.4 MB

typedef __attribute__((ext_vector_type(8))) short bhalf8;
typedef __attribute__((ext_vector_type(4))) float floatx4;

__device__ __forceinline__ unsigned short f2b(float f){
  unsigned u = __float_as_uint(f);
  return (unsigned short)((u + 0x7fffu + ((u >> 16) & 1u)) >> 16);
}
__device__ __forceinline__ float b2f(unsigned short h){
  return __uint_as_float(((unsigned)h) << 16);
}
__device__ __forceinline__ void split2(float f, unsigned short* hi, unsigned short* lo){
  unsigned short h = f2b(f);
  *hi = h;
  *lo = f2b(f - b2f(h));
}

// async global->LDS, 16B per lane, LDS dest = wave-uniform base + lane*16 (m97 pattern)
__device__ __forceinline__ void gload_lds16(const unsigned short* g, void* lds){
  __builtin_amdgcn_global_load_lds(
      (const __attribute__((address_space(1))) void*)g,
      (__attribute__((address_space(3))) void*)lds, 16, 0, 0);
}

// ---------------- fused prep: transpose x -> xf/xh/xl | cast weights | zero counters ----
__global__ __launch_bounds__(256) void k_prep(const float* __restrict__ x, float* __restrict__ xf,
    unsigned short* __restrict__ xh, unsigned short* __restrict__ xl,
    const float* __restrict__ Wq, const float* __restrict__ Wk, const float* __restrict__ Wv,
    const float* __restrict__ Wm, const float* __restrict__ f1, const float* __restrict__ f2,
    unsigned short* __restrict__ dhi, unsigned short* __restrict__ dlo, int* __restrict__ ctr){
  int bid = blockIdx.x;
  int t = threadIdx.x;
  if (bid < 400){
    __shared__ float tile[32][33];
    int b = bid / 200; int r = bid - b*200;
    int d0 = (r / 25) * 32, n0 = (r % 25) * 32;
    int tx = t & 31, ty = t >> 5;
    #pragma unroll
    for (int i = 0; i < 4; i++){
      int d = d0 + ty + i*8, n = n0 + tx;
      if (n < NTOK) tile[ty + i*8][tx] = x[((size_t)b*DM + d)*NTOK + n];
    }
    __syncthreads();
    #pragma unroll
    for (int i = 0; i < 4; i++){
      int n = n0 + ty + i*8, d = d0 + tx;
      if (n < NTOK){
        float v = tile[tx][ty + i*8];
        size_t o = ((size_t)b*NTOK + n)*DM + d;
        xf[o] = v;
        unsigned short h, l; split2(v, &h, &l);
        xh[o] = h; xl[o] = l;
      }
    }
  } else {
    if (bid == 400 && t < 4) ctr[t] = 0;
    int i = ((bid - 400)*256 + t)*4;
    const float* src; int off;
    if (i < 65536){ src=Wq; off=i; }
    else if (i < 131072){ src=Wk; off=i-65536; }
    else if (i < 196608){ src=Wv; off=i-131072; }
    else if (i < 262144){ src=Wm; off=i-196608; }
    else if (i < 524288){ src=f1; off=i-262144; }
    else { src=f2; off=i-524288; }
    float4 fv = *(const float4*)(src + off);
    ushort4 oh, ol;
    split2(fv.x, &oh.x, &ol.x);
    split2(fv.y, &oh.y, &ol.y);
    split2(fv.z, &oh.z, &ol.z);
    split2(fv.w, &oh.w, &ol.w);
    *(ushort4*)(dhi + i) = oh;
    *(ushort4*)(dlo + i) = ol;
  }
}

// ---- split-bf16 MFMA GEMM tile (r4-verified layout); WST = W row stride; K-loop is 256 ----
// MODE_C 1: qkv split + bf16 echo (qb16 row-major, kb16 row-major, vT16 transposed)
template<int WST, int ACT, bool HASB, int MODE_C>
__device__ __forceinline__ void mgemm_tile(int bx, int by,
    const unsigned short* __restrict__ Ah0, const unsigned short* __restrict__ Al0,
    const unsigned short* __restrict__ Wh, const unsigned short* __restrict__ Wl,
    const float* __restrict__ bias,
    float* __restrict__ C0, float* __restrict__ C1, float* __restrict__ C2,
    unsigned short* __restrict__ qb16, unsigned short* __restrict__ kb16, unsigned short* __restrict__ vt16,
    int M, int NN){
  int t = threadIdx.x;
  int w = t >> 6, l = t & 63;
  int lm = l & 15;
  int lk = (l >> 4) << 3;
  int mw = bx * 64 + (w >> 1) * 32;
  int nw = by * 64 + (w & 1) * 32;
  floatx4 acc[2][2] = {};
  int ar0 = mw + lm, ar1 = ar0 + 16;
  int ga0 = (ar0 < M) ? ar0 : 0;
  int ga1 = (ar1 < M) ? ar1 : 0;
  int nr0 = nw + lm, nr1 = nr0 + 16;
  #pragma unroll 4
  for (int k0 = 0; k0 < 256; k0 += 32){
    int ak = k0 + lk;
    bhalf8 a0h = *(const bhalf8*)(Ah0 + (size_t)ga0*256 + ak);
    bhalf8 a0l = *(const bhalf8*)(Al0 + (size_t)ga0*256 + ak);
    bhalf8 a1h = *(const bhalf8*)(Ah0 + (size_t)ga1*256 + ak);
    bhalf8 a1l = *(const bhalf8*)(Al0 + (size_t)ga1*256 + ak);
    bhalf8 w0h = *(const bhalf8*)(Wh + (size_t)nr0*WST + ak);
    bhalf8 w0l = *(const bhalf8*)(Wl + (size_t)nr0*WST + ak);
    bhalf8 w1h = *(const bhalf8*)(Wh + (size_t)nr1*WST + ak);
    bhalf8 w1l = *(const bhalf8*)(Wl + (size_t)nr1*WST + ak);
    acc[0][0] = __builtin_amdgcn_mfma_f32_16x16x32_bf16(a0h, w0h, acc[0][0], 0, 0, 0);
    acc[0][0] = __builtin_amdgcn_mfma_f32_16x16x32_bf16(a0l, w0h, acc[0][0], 0, 0, 0);
    acc[0][0] = __builtin_amdgcn_mfma_f32_16x16x32_bf16(a0h, w0l, acc[0][0], 0, 0, 0);
    acc[0][1] = __builtin_amdgcn_mfma_f32_16x16x32_bf16(a0h, w1h, acc[0][1], 0, 0, 0);
    acc[0][1] = __builtin_amdgcn_mfma_f32_16x16x32_bf16(a0l, w1h, acc[0][1], 0, 0, 0);
    acc[0][1] = __builtin_amdgcn_mfma_f32_16x16x32_bf16(a0h, w1l, acc[0][1], 0, 0, 0);
    acc[1][0] = __builtin_amdgcn_mfma_f32_16x16x32_bf16(a1h, w0h, acc[1][0], 0, 0, 0);
    acc[1][0] = __builtin_amdgcn_mfma_f32_16x16x32_bf16(a1l, w0h, acc[1][0], 0, 0, 0);
    acc[1][0] = __builtin_amdgcn_mfma_f32_16x16x32_bf16(a1h, w0l, acc[1][0], 0, 0, 0);
    acc[1][1] = __builtin_amdgcn_mfma_f32_16x16x32_bf16(a1h, w1h, acc[1][1], 0, 0, 0);
    acc[1][1] = __builtin_amdgcn_mfma_f32_16x16x32_bf16(a1l, w1h, acc[1][1], 0, 0, 0);
    acc[1][1] = __builtin_amdgcn_mfma_f32_16x16x32_bf16(a1h, w1l, acc[1][1], 0, 0, 0);
  }
  int dr = (l >> 4) << 2;
  #pragma unroll
  for (int mt = 0; mt < 2; mt++){
    #pragma unroll
    for (int r = 0; r < 4; r++){
      int m = mw + mt*16 + dr + r;
      if (m >= M) continue;
      #pragma unroll
      for (int nt = 0; nt < 2; nt++){
        int jj = nw + nt*16 + lm;
        float v = acc[mt][nt][r];
        if (HASB) v += bias[jj];
        if (ACT == 1) v = fmaxf(v, 0.f);
        if (MODE_C == 1){
          int b3 = m / NTOK, n = m - b3*NTOK;
          int rr = n / 28, cc = n - rr*28;
          int wo = ((rr/7)*4 + (cc/7))*WS + (rr%7)*7 + (cc%7);
          float* Cx = (jj < 256) ? C0 : ((jj < 512) ? C1 : C2);
          Cx[((size_t)(b3*NTOK + wo))*DM + (jj & 255)] = v;
          unsigned short bv16 = f2b(v);
          if (jj < 256)      qb16[((size_t)(b3*NTOK + wo))*256 + jj] = bv16;
          else if (jj < 512) kb16[((size_t)(b3*800 + wo))*256 + (jj - 256)] = bv16;
          else               vt16[((size_t)(b3*256 + (jj - 512)))*800 + wo] = bv16;
        } else {
          C0[(size_t)m*(size_t)NN + jj] = v;
        }
      }
    }
  }
}

// qkv (by<12) + y1a = xh@W1[:, :256] + fc1b (by>=12, off critical path)
__global__ __launch_bounds__(256) void k_qkv_y1a(const unsigned short* __restrict__ Ah, const unsigned short* __restrict__ Al,
    const unsigned short* __restrict__ Wqkvh, const unsigned short* __restrict__ Wqkvl,
    const unsigned short* __restrict__ W1h, const unsigned short* __restrict__ W1l,
    const float* __restrict__ fc1b,
    float* __restrict__ q, float* __restrict__ k, float* __restrict__ v,
    unsigned short* __restrict__ qb16, unsigned short* __restrict__ kb16, unsigned short* __restrict__ vt16,
    float* __restrict__ y1a){
  if (blockIdx.y < 12){
    mgemm_tile<256,0,false,1>(blockIdx.x, blockIdx.y, Ah, Al, Wqkvh, Wqkvl, nullptr,
                              q, k, v, qb16, kb16, vt16, MTOT, 768);
  } else {
    mgemm_tile<512,0,true,0>(blockIdx.x, blockIdx.y - 12, Ah, Al, W1h, W1l, fc1b,
                             y1a, nullptr, nullptr, nullptr, nullptr, nullptr, MTOT, 512);
  }
}

// ---------------- fused means + sim + top-8 + multiplicity (last-block tail) ----------------
__global__ __launch_bounds__(256) void k_meanstopk(const float* __restrict__ q, const float* __restrict__ k,
    const float* __restrict__ v, float* __restrict__ qm, float* __restrict__ km, float* __restrict__ vm,
    unsigned short* __restrict__ kb16, unsigned short* __restrict__ vt16,
    int* __restrict__ cnt, int* __restrict__ ctr){
  int b = blockIdx.x >> 4, w = blockIdx.x & 15;
  int t = threadIdx.x;
  size_t base = ((size_t)b*NTOK + w*WS)*DM + t;
  float sq=0.f, sk=0.f, sv=0.f;
  for (int p=0;p<WS;p++){ sq += q[base + (size_t)p*DM]; sk += k[base + (size_t)p*DM]; sv += v[base + (size_t)p*DM]; }
  size_t o = ((size_t)b*NW + w)*DM + t;
  float kmv = sk*(1.f/49.f), vmv = sv*(1.f/49.f);
  qm[o]=sq*(1.f/49.f); km[o]=kmv; vm[o]=vmv;
  // bf16 echoes into the attn staging buffers (mean rows 784..799)
  kb16[((size_t)(b*800 + NTOK + w))*256 + t] = f2b(kmv);
  vt16[((size_t)(b*256 + t))*800 + NTOK + w] = f2b(vmv);

  __threadfence();
  __shared__ int lastFlag;
  if (t == 0) lastFlag = (atomicAdd(&ctr[b], 1) == NW-1);
  __syncthreads();
  if (!lastFlag) return;
  __threadfence();

  __shared__ float sim[16][16];
  __shared__ int sidx[16][KTOP];
  {
    int wq = t >> 4, wk = t & 15;
    const float* qp = qm + ((size_t)b*NW + wq)*DM;
    const float* kp = km + ((size_t)b*NW + wk)*DM;
    float d0=0,d1=0,d2=0,d3=0;
    for (int i=0;i<DM;i+=4){
      d0=fmaf(qp[i+0],kp[i+0],d0); d1=fmaf(qp[i+1],kp[i+1],d1);
      d2=fmaf(qp[i+2],kp[i+2],d2); d3=fmaf(qp[i+3],kp[i+3],d3);
    }
    sim[wq][wk] = (d0+d1)+(d2+d3);
  }
  __syncthreads();
  if (t < 16){
    float vals[16];
    #pragma unroll
    for (int i=0;i<16;i++) vals[i]=sim[t][i];
    for (int s=0;s<KTOP;s++){
      int best=0; float bv=vals[0];
      for (int i=1;i<16;i++) if (vals[i] > bv){ bv=vals[i]; best=i; }
      sidx[t][s] = best;
      vals[best] = -1e30f;
    }
  }
  __syncthreads();
  if (t < 16){
    int c = 0;
    const int* si = &sidx[0][0];
    #pragma unroll 8
    for (int j=0;j<NW*KTOP;j++) c += (si[j] == t) ? 1 : 0;
    cnt[b*NW + t] = c;
  }
}

// ---------------- MFMA dedup attention, async-staged from pre-packed bf16 ----------------
// K staging: kb16[b][800][256] row-major; V staging: vT16[b][256][800] transposed.
// global_load_lds 16B/lane, LDS dest = frag-linear (lane-contiguous) = Kf/Vf layout.
__global__ __launch_bounds__(256) void k_attn(const unsigned short* __restrict__ qb16,
    const unsigned short* __restrict__ kb16, const unsigned short* __restrict__ vt16,
    const int* __restrict__ cnt,
    unsigned short* __restrict__ mh, unsigned short* __restrict__ ml){
  __shared__ __align__(16) short Kf[2][128][8];
  __shared__ __align__(16) short Vf[2][128][8];
  __shared__ float Wt[800];
  __shared__ __align__(16) short Pl[4][16][40];

  int qt = blockIdx.x;
  int bh = blockIdx.y;
  int b = bh >> 3, h = bh & 7;
  int t = threadIdx.x;
  int w = t >> 6, l = t & 63;
  int lg = l >> 4, lm = l & 15;
  const float scale = 0.17677669529663687f;

  for (int s = t; s < 800; s += 256)
    Wt[s] = (s < NTOK) ? (float)cnt[b*NW + s/WS] : 16.0f;

  bhalf8 qa;
  {
    int qrow = qt*64 + w*16 + lm;
    int qr = (qrow < NTOK) ? qrow : 0;
    qa = *(const bhalf8*)(qb16 + ((size_t)(b*NTOK + qr))*256 + h*DH + lg*8);
  }

  floatx4 o0 = {0.f,0.f,0.f,0.f}, o1 = {0.f,0.f,0.f,0.f};
  float rs[4] = {0.f,0.f,0.f,0.f};

  // per-wave async stage: waves 0,1 -> K tiles 0,1; waves 2,3 -> V^T tiles 0,1
  auto stage = [&](int c, int buf){
    if (w < 2){
      int s = c*32 + w*16 + lm;                       // key row (incl. mean rows)
      const unsigned short* gp = kb16 + ((size_t)(b*800 + s))*256 + h*DH + lg*8;
      gload_lds16(gp, &Kf[buf][w*64][0]);
    } else {
      int Td = w - 2;
      int dmv = h*DH + Td*16 + lm;                    // head dim
      const unsigned short* gp = vt16 + ((size_t)(b*256 + dmv))*800 + c*32 + lg*8;
      gload_lds16(gp, &Vf[buf][Td*64][0]);
    }
  };

  stage(0, 0);
  __syncthreads();

  for (int c = 0; c < 25; c++){
    int buf = c & 1;
    if (c + 1 < 25) stage(c + 1, buf ^ 1);

    bhalf8 k0 = *(const bhalf8*)&Kf[buf][l][0];
    bhalf8 k1 = *(const bhalf8*)&Kf[buf][64 + l][0];
    floatx4 z = {0.f,0.f,0.f,0.f};
    floatx4 s0 = __builtin_amdgcn_mfma_f32_16x16x32_bf16(qa, k0, z, 0, 0, 0);
    floatx4 s1 = __builtin_amdgcn_mfma_f32_16x16x32_bf16(qa, k1, z, 0, 0, 0);
    float w0 = Wt[c*32 + lm];
    float w1 = Wt[c*32 + 16 + lm];
    #pragma unroll
    for (int r = 0; r < 4; r++){
      float p0 = w0 * __expf(s0[r] * scale);
      float p1 = w1 * __expf(s1[r] * scale);
      unsigned short pb0 = f2b(p0), pb1 = f2b(p1);
      rs[r] += b2f(pb0) + b2f(pb1);
      Pl[w][lg*4 + r][lm] = (short)pb0;
      Pl[w][lg*4 + r][16 + lm] = (short)pb1;
    }
    bhalf8 pa = *(const bhalf8*)&Pl[w][lm][lg*8];
    bhalf8 v0 = *(const bhalf8*)&Vf[buf][l][0];
    bhalf8 v1 = *(const bhalf8*)&Vf[buf][64 + l][0];
    o0 = __builtin_amdgcn_mfma_f32_16x16x32_bf16(pa, v0, o0, 0, 0, 0);
    o1 = __builtin_amdgcn_mfma_f32_16x16x32_bf16(pa, v1, o1, 0, 0, 0);

    __syncthreads();   // drains vmcnt (async stage) + lgkm before buffer swap
  }

  #pragma unroll
  for (int r = 0; r < 4; r++){
    float v = rs[r];
    v += __shfl_xor(v, 1); v += __shfl_xor(v, 2);
    v += __shfl_xor(v, 4); v += __shfl_xor(v, 8);
    rs[r] = v;
  }
  #pragma unroll
  for (int r = 0; r < 4; r++){
    int qq = qt*64 + w*16 + lg*4 + r;
    if (qq < NTOK){
      float inv = 1.f / rs[r];
      size_t off = ((size_t)(b*NTOK + qq))*DM + h*DH;
      unsigned short hh, ll2;
      split2(o0[r] * inv, &hh, &ll2);
      mh[off + lm] = hh; ml[off + lm] = ll2;
      split2(o1[r] * inv, &hh, &ll2);
      mh[off + 16 + lm] = hh; ml[off + 16 + lm] = ll2;
    }
  }
}

// ---------------- fused Wm GEMM + LN1 + fc1b (m2 stays in LDS) -> y1 (r9-verified) ----------
__global__ __launch_bounds__(256) void k_wm_fc1(const unsigned short* __restrict__ mh, const unsigned short* __restrict__ ml,
    const unsigned short* __restrict__ Wmh, const unsigned short* __restrict__ Wml,
    const unsigned short* __restrict__ W1h, const unsigned short* __restrict__ W1l,
    const float* __restrict__ gg, const float* __restrict__ bb,
    const float* __restrict__ y1a, float* __restrict__ y1){
  __shared__ __align__(16) float Cs[16][261];
  __shared__ __align__(16) short M2h[16][264], M2l[16][264];
  __shared__ float wps[4][16], wpq[4][16], smu[16], srs[16];
  int m0 = blockIdx.x * 16;
  int t = threadIdx.x, w = t >> 6, l = t & 63;
  int lm = l & 15, lg = l >> 4;

  floatx4 acc[4] = {};
  int arow = m0 + lm;
  #pragma unroll 2
  for (int k0 = 0; k0 < 256; k0 += 32){
    int ak = k0 + lg*8;
    bhalf8 ah = *(const bhalf8*)(mh + (size_t)arow*256 + ak);
    bhalf8 al = *(const bhalf8*)(ml + (size_t)arow*256 + ak);
    #pragma unroll
    for (int ct = 0; ct < 4; ct++){
      int n = w*64 + ct*16 + lm;
      bhalf8 wh_ = *(const bhalf8*)(Wmh + (size_t)n*256 + ak);
      bhalf8 wl_ = *(const bhalf8*)(Wml + (size_t)n*256 + ak);
      acc[ct] = __builtin_amdgcn_mfma_f32_16x16x32_bf16(ah, wh_, acc[ct], 0, 0, 0);
      acc[ct] = __builtin_amdgcn_mfma_f32_16x16x32_bf16(al, wh_, acc[ct], 0, 0, 0);
      acc[ct] = __builtin_amdgcn_mfma_f32_16x16x32_bf16(ah, wl_, acc[ct], 0, 0, 0);
    }
  }
  float s1[4] = {0.f,0.f,0.f,0.f}, s2[4] = {0.f,0.f,0.f,0.f};
  #pragma unroll
  for (int ct = 0; ct < 4; ct++){
    #pragma unroll
    for (int r = 0; r < 4; r++){
      float v = acc[ct][r];
      Cs[lg*4 + r][w*64 + ct*16 + lm] = v;
      s1[r] += v; s2[r] += v*v;
    }
  }
  #pragma unroll
  for (int r = 0; r < 4; r++){
    #pragma unroll
    for (int mk = 1; mk < 16; mk <<= 1){
      s1[r] += __shfl_xor(s1[r], mk);
      s2[r] += __shfl_xor(s2[r], mk);
    }
  }
  if (lm == 0){
    #pragma unroll
    for (int r = 0; r < 4; r++){ wps[w][lg*4+r] = s1[r]; wpq[w][lg*4+r] = s2[r]; }
  }
  __syncthreads();
  if (t < 16){
    float a = wps[0][t]+wps[1][t]+wps[2][t]+wps[3][t];
    float qq = wpq[0][t]+wpq[1][t]+wpq[2][t]+wpq[3][t];
    float mu = a * (1.f/DM);
    float var = qq * (1.f/DM) - mu*mu;
    smu[t] = mu; srs[t] = rsqrtf(var + 1e-5f);
  }
  __syncthreads();
  {
    float g = gg[t], bv2 = bb[t];
    #pragma unroll
    for (int rr = 0; rr < 16; rr++){
      float o = (Cs[rr][t] - smu[rr]) * srs[rr] * g + bv2;
      unsigned short hh, ll2; split2(o, &hh, &ll2);
      M2h[rr][t] = (short)hh; M2l[rr][t] = (short)ll2;
    }
  }
  __syncthreads();

  #pragma unroll
  for (int p = 0; p < 2; p++){
    floatx4 a2[4] = {};
    #pragma unroll 2
    for (int k0 = 0; k0 < 256; k0 += 32){
      int ak = k0 + lg*8;
      bhalf8 ah2 = *(const bhalf8*)&M2h[lm][ak];
      bhalf8 al2 = *(const bhalf8*)&M2l[lm][ak];
      #pragma unroll
      for (int ct = 0; ct < 4; ct++){
        int j = p*256 + w*64 + ct*16 + lm;
        bhalf8 wh_ = *(const bhalf8*)(W1h + (size_t)j*512 + 256 + ak);
        bhalf8 wl_ = *(const bhalf8*)(W1l + (size_t)j*512 + 256 + ak);
        a2[ct] = __builtin_amdgcn_mfma_f32_16x16x32_bf16(ah2, wh_, a2[ct], 0, 0, 0);
        a2[ct] = __builtin_amdgcn_mfma_f32_16x16x32_bf16(al2, wh_, a2[ct], 0, 0, 0);
        a2[ct] = __builtin_amdgcn_mfma_f32_16x16x32_bf16(ah2, wl_, a2[ct], 0, 0, 0);
      }
    }
    #pragma unroll
    for (int ct = 0; ct < 4; ct++){
      #pragma unroll
      for (int r = 0; r < 4; r++){
        int m = m0 + lg*4 + r;
        int j = p*256 + w*64 + ct*16 + lm;
        float v = a2[ct][r] + y1a[(size_t)m*512 + j];
        y1[(size_t)m*512 + j] = fmaxf(v, 0.f);
      }
    }
  }
}

// ---------------- depthwise conv 3x3 SAME + bias + exact gelu -> hi/lo bf16 ----------------
__global__ __launch_bounds__(256) void k_dwconv(const float* __restrict__ y1, const float* __restrict__ w,
    const float* __restrict__ bias, unsigned short* __restrict__ gh, unsigned short* __restrict__ gl){
  int m = blockIdx.x;
  int b = m / NTOK, n = m - b*NTOK;
  int r = n / 28, c = n - r*28;
  for (int ch = threadIdx.x; ch < 512; ch += 256){
    float acc = bias[ch];
    #pragma unroll
    for (int ky=-1; ky<=1; ky++){
      int rr = r + ky;
      if (rr < 0 || rr >= 28) continue;
      #pragma unroll
      for (int kx=-1; kx<=1; kx++){
        int cc = c + kx;
        if (cc < 0 || cc >= 28) continue;
        acc = fmaf(y1[((size_t)b*NTOK + rr*28+cc)*512 + ch], w[ch*9 + (ky+1)*3 + (kx+1)], acc);
      }
    }
    float x = acc;
    float ge = 0.5f*x*(1.f + erff(x*0.70710678118654752f));
    unsigned short hh, ll2; split2(ge, &hh, &ll2);
    gh[(size_t)m*512 + ch] = hh; gl[(size_t)m*512 + ch] = ll2;
  }
}

// ---------------- fused fc2 GEMM + bias + LN2 + residual + transposed store (r7-verified) ----
__global__ __launch_bounds__(256) void k_fc2_ln2(const unsigned short* __restrict__ gh, const unsigned short* __restrict__ gl,
    const unsigned short* __restrict__ Wh, const unsigned short* __restrict__ Wl,
    const float* __restrict__ bias, const float* __restrict__ gg, const float* __restrict__ bb,
    const float* __restrict__ xf, float* __restrict__ out){
  __shared__ __align__(16) float Cs[16][261];
  __shared__ float wps[4][16], wpq[4][16], smu[16], srs[16];
  int m0 = blockIdx.x * 16;
  int t = threadIdx.x, w = t >> 6, l = t & 63;
  int lm = l & 15, lg = l >> 4;
  floatx4 acc[4] = {};
  int arow = m0 + lm;
  #pragma unroll 2
  for (int k0 = 0; k0 < 512; k0 += 32){
    int ak = k0 + lg*8;
    bhalf8 ah = *(const bhalf8*)(gh + (size_t)arow*512 + ak);
    bhalf8 al = *(const bhalf8*)(gl + (size_t)arow*512 + ak);
    #pragma unroll
    for (int ct = 0; ct < 4; ct++){
      int n = w*64 + ct*16 + lm;
      bhalf8 wh_ = *(const bhalf8*)(Wh + (size_t)n*512 + ak);
      bhalf8 wl_ = *(const bhalf8*)(Wl + (size_t)n*512 + ak);
      acc[ct] = __builtin_amdgcn_mfma_f32_16x16x32_bf16(ah, wh_, acc[ct], 0, 0, 0);
      acc[ct] = __builtin_amdgcn_mfma_f32_16x16x32_bf16(al, wh_, acc[ct], 0, 0, 0);
      acc[ct] = __builtin_amdgcn_mfma_f32_16x16x32_bf16(ah, wl_, acc[ct], 0, 0, 0);
    }
  }
  float s1[4] = {0.f,0.f,0.f,0.f}, s2[4] = {0.f,0.f,0.f,0.f};
  #pragma unroll
  for (int ct = 0; ct < 4; ct++){
    float bv = bias[w*64 + ct*16 + lm];
    #pragma unroll
    for (int r = 0; r < 4; r++){
      float v = acc[ct][r] + bv;
      Cs[lg*4 + r][w*64 + ct*16 + lm] = v;
      s1[r] += v; s2[r] += v*v;
    }
  }
  #pragma unroll
  for (int r = 0; r < 4; r++){
    #pragma unroll
    for (int mk = 1; mk < 16; mk <<= 1){
      s1[r] += __shfl_xor(s1[r], mk);
      s2[r] += __shfl_xor(s2[r], mk);
    }
  }
  if (lm == 0){
    #pragma unroll
    for (int r = 0; r < 4; r++){ wps[w][lg*4+r] = s1[r]; wpq[w][lg*4+r] = s2[r]; }
  }
  __syncthreads();
  if (t < 16){
    float a = wps[0][t]+wps[1][t]+wps[2][t]+wps[3][t];
    float qq = wpq[0][t]+wpq[1][t]+wpq[2][t]+wpq[3][t];
    float mu = a * (1.f/DM);
    float var = qq * (1.f/DM) - mu*mu;
    smu[t] = mu; srs[t] = rsqrtf(var + 1e-5f);
  }
  __syncthreads();
  {
    float g = gg[t], bv2 = bb[t];
    #pragma unroll
    for (int rr = 0; rr < 16; rr++){
      int m = m0 + rr;
      Cs[rr][t] = (Cs[rr][t] - smu[rr]) * srs[rr] * g + bv2 + xf[(size_t)m*DM + t];
    }
  }
  __syncthreads();
  {
    int r3 = t & 15;
    int d0 = (t >> 4) * 16;
    int m = m0 + r3;
    int b2 = (m < NTOK) ? 0 : 1;
    int n2 = m - b2*NTOK;
    #pragma unroll
    for (int dd = 0; dd < 16; dd++){
      int d = d0 + dd;
      out[((size_t)(b2*DM + d))*NTOK + n2] = Cs[r3][d];
    }
  }
}

extern "C" void kernel_launch(void* const* d_in, const int* in_sizes, int n_in,
                              void* d_out, int out_size, void* d_ws, size_t ws_size,
                              hipStream_t stream){
  const float* x    = (const float*)d_in[0];
  const float* Wq   = (const float*)d_in[1];
  const float* Wk   = (const float*)d_in[2];
  const float* Wv   = (const float*)d_in[3];
  const float* Wm   = (const float*)d_in[4];
  const float* ln1g = (const float*)d_in[5];
  const float* ln1b = (const float*)d_in[6];
  const float* fc1w = (const float*)d_in[7];
  const float* fc1b = (const float*)d_in[8];
  const float* dww  = (const float*)d_in[9];
  const float* dwb  = (const float*)d_in[10];
  const float* fc2w = (const float*)d_in[11];
  const float* fc2b = (const float*)d_in[12];
  const float* ln2g = (const float*)d_in[13];
  const float* ln2b = (const float*)d_in[14];

  float* ws  = (float*)d_ws;
  float* out = (float*)d_out;
  float* xf   = ws + O_XF;
  unsigned short* xh = (unsigned short*)(ws + O_XH);
  unsigned short* xl = (unsigned short*)(ws + O_XL);
  float* qb   = ws + O_Q;
  float* kb   = ws + O_K;
  float* vb   = ws + O_V;
  unsigned short* qb16 = (unsigned short*)(ws + O_QB);
  unsigned short* kb16 = (unsigned short*)(ws + O_KB);
  unsigned short* vt16 = (unsigned short*)(ws + O_VT);
  float* qm   = ws + O_QM;
  float* km   = ws + O_KM;
  float* vm   = ws + O_VM;
  int*   ctr  = (int*)(ws + O_CTR);
  int*   cnt  = (int*)(ws + O_CNT);
  unsigned short* whi = (unsigned short*)(ws + O_WHI);
  unsigned short* wlo = (unsigned short*)(ws + O_WLO);
  unsigned short* mhp = (unsigned short*)(ws + O_MH);
  unsigned short* mlp = (unsigned short*)(ws + O_ML);
  float* y1a  = ws + O_Y1A;
  float* y1   = ws + O_Y1;
  unsigned short* gh  = (unsigned short*)(ws + O_GH);
  unsigned short* gl  = (unsigned short*)(ws + O_GL);

  unsigned short* wqkv_h = whi,        *wqkv_l = wlo;
  unsigned short* wm_h   = whi+196608, *wm_l   = wlo+196608;
  unsigned short* w1_h   = whi+262144, *w1_l   = wlo+262144;
  unsigned short* w2_h   = whi+524288, *w2_l   = wlo+524288;

  k_prep<<<1040, 256, 0, stream>>>(x, xf, xh, xl, Wq, Wk, Wv, Wm, fc1w, fc2w, whi, wlo, ctr);
  k_qkv_y1a<<<dim3(25,20), 256, 0, stream>>>(xh, xl, wqkv_h, wqkv_l, w1_h, w1_l, fc1b,
                                             qb, kb, vb, qb16, kb16, vt16, y1a);
  k_meanstopk<<<BB*NW, 256, 0, stream>>>(qb, kb, vb, qm, km, vm, kb16, vt16, cnt, ctr);
  k_attn<<<dim3(13,16), 256, 0, stream>>>(qb16, kb16, vt16, cnt, mhp, mlp);
  k_wm_fc1<<<98, 256, 0, stream>>>(mhp, mlp, wm_h, wm_l, w1_h, w1_l, ln1g, ln1b, y1a, y1);
  k_dwconv<<<MTOT, 256, 0, stream>>>(y1, dww, dwb, gh, gl);
  k_fc2_ln2<<<98, 256, 0, stream>>>(gh, gl, w2_h, w2_l, fc2b, ln2g, ln2b, xf, out);
}